// Round 3
// baseline (223.704 us; speedup 1.0000x reference)
//
#include <hip/hip_runtime.h>
#include <hip/hip_bf16.h>

// Problem constants
#define L_DIM 128
#define N_DIM 32
#define C_DIM 128
#define K_DIM 128   // DIM_MLP
#define OUT_DIM 128

typedef __attribute__((ext_vector_type(8))) short short8;
typedef __attribute__((ext_vector_type(4))) float float4v;
typedef __attribute__((ext_vector_type(2))) float float2v;

static __device__ __forceinline__ short bf16_bits(float f) {
    __bf16 h = (__bf16)f;   // RNE
    return __builtin_bit_cast(short, h);
}

// ---------------------------------------------------------------------------
// Kernel 1: precompute.
//   blocks 0..511 : 8 flat rows each. P = x·W1a ; Q = x·W1b + b1 ;
//                   V = relu(x·Vw1+vb1)·Vw2 + vb2
//   blocks 512..575: W2s = attn_w2 swizzled into bf16 MFMA B-fragment order
// ---------------------------------------------------------------------------
__global__ __launch_bounds__(256) void k_pre(
    const float* __restrict__ x,
    const float* __restrict__ attn_w1, const float* __restrict__ attn_b1,
    const float* __restrict__ attn_w2,
    const float* __restrict__ value_w1, const float* __restrict__ value_b1,
    const float* __restrict__ value_w2, const float* __restrict__ value_b2,
    float* __restrict__ P, float* __restrict__ Q, float* __restrict__ V,
    short* __restrict__ W2s)
{
    int bid = blockIdx.x;
    int tid = threadIdx.x;
    if (bid >= 512) {
        // W2 swizzle: element e = ((((ct*4+mi)*4+quad)*16+col)*8+idx)
        int e = (bid - 512) * 256 + tid;              // 64*256 = 16384 elems
        int idx  = e & 7;
        int colr = (e >> 3) & 15;
        int quad = (e >> 7) & 3;
        int mi   = (e >> 9) & 3;
        int ct   = e >> 11;
        int k = quad * 8 + 32 * mi + idx;
        int c = ct * 16 + colr;
        W2s[e] = bf16_bits(attn_w2[k * OUT_DIM + c]);
        return;
    }

    __shared__ float xs[8][C_DIM];
    __shared__ float hvs[8][K_DIM];
    int r0 = bid * 8;                                  // first flat row (i*N+b)

    {   // cooperative load of 8 x-rows (1024 floats, float4 per thread)
        int f = tid * 4;
        int row = f >> 7, c = f & 127;
        *(float4v*)(&xs[row][c]) = *(const float4v*)(x + (r0 + row) * C_DIM + c);
    }
    __syncthreads();

    int ks   = tid & 127;      // output column k (or c)
    int half = tid >> 7;       // rows 0-3 vs 4-7

    float pacc[4] = {0,0,0,0}, qacc[4] = {0,0,0,0}, hacc[4] = {0,0,0,0};
    #pragma unroll 4
    for (int c = 0; c < C_DIM; ++c) {
        float wa = attn_w1[c * K_DIM + ks];
        float wb = attn_w1[(C_DIM + c) * K_DIM + ks];
        float wv = value_w1[c * K_DIM + ks];
        #pragma unroll
        for (int r = 0; r < 4; ++r) {
            float xr = xs[half * 4 + r][c];
            pacc[r] = fmaf(xr, wa, pacc[r]);
            qacc[r] = fmaf(xr, wb, qacc[r]);
            hacc[r] = fmaf(xr, wv, hacc[r]);
        }
    }
    float b1 = attn_b1[ks], vb1 = value_b1[ks];
    #pragma unroll
    for (int r = 0; r < 4; ++r) {
        int rr = r0 + half * 4 + r;
        int i = rr >> 5, b = rr & 31;                  // rr = i*N + b
        P[(b * L_DIM + i) * K_DIM + ks] = pacc[r];
        Q[(b * L_DIM + i) * K_DIM + ks] = qacc[r] + b1;
        hvs[half * 4 + r][ks] = fmaxf(hacc[r] + vb1, 0.f);
    }
    __syncthreads();

    float vacc[4] = {0,0,0,0};
    #pragma unroll 4
    for (int k = 0; k < K_DIM; ++k) {
        float w = value_w2[k * OUT_DIM + ks];
        #pragma unroll
        for (int r = 0; r < 4; ++r)
            vacc[r] = fmaf(hvs[half * 4 + r][k], w, vacc[r]);
    }
    float vb2 = value_b2[ks];
    #pragma unroll
    for (int r = 0; r < 4; ++r) {
        int rr = r0 + half * 4 + r;
        int i = rr >> 5, b = rr & 31;
        V[(b * L_DIM + i) * OUT_DIM + ks] = vacc[r] + vb2;
    }
}

// ---------------------------------------------------------------------------
// Kernel 2: fused pairwise-MLP + j-reduce + Sv (no LDS A round-trip).
//   block = (b, itile); 4 waves; wave w owns i = itile*4 + w.
//   8 rounds of 16 j's. Per round: each lane builds its OWN A-fragment
//   h[j=col][k] = relu(P_reg + Q_lds[col]) (bf16), MFMAs vs register-resident
//   W2 B-frags, scales rows by V (scalar global loads, L2-hot) into acc, and
//   accumulates sv = sum_j V for the folded b2*Sv term. One barrier/round.
// ---------------------------------------------------------------------------
#define QSTR 132   // 128 + 4-float pad: build reads & staging writes 2-way max

__global__ __launch_bounds__(256)
__attribute__((amdgpu_waves_per_eu(2, 2)))
void k_main(
    const float* __restrict__ P, const float* __restrict__ Q,
    const float* __restrict__ V,
    const short* __restrict__ W2s, const float* __restrict__ attn_b2,
    float* __restrict__ out)
{
    __shared__ float Qb[2][16 * QSTR];   // double-buffered Q tile (17 KB)

    int b     = blockIdx.x >> 5;
    int itile = blockIdx.x & 31;
    int tid   = threadIdx.x;
    int wave  = tid >> 6;
    int lane  = tid & 63;
    int quad  = lane >> 4;
    int col   = lane & 15;
    int i_g   = itile * 4 + wave;

    // B fragments: register-resident W2 (swizzle verified rounds 1-2)
    short8 bfrag[8][4];
    const short8* w2p = (const short8*)W2s;
    #pragma unroll
    for (int ct = 0; ct < 8; ++ct)
        #pragma unroll
        for (int mi = 0; mi < 4; ++mi)
            bfrag[ct][mi] = w2p[((ct * 4 + mi) * 4 + quad) * 16 + col];

    // P fragment (this wave's i), k-pattern matches A-frags; j-invariant
    float4v p[4][2];
    const float* Pr = P + (b * L_DIM + i_g) * K_DIM;
    #pragma unroll
    for (int mi = 0; mi < 4; ++mi) {
        int k0 = quad * 8 + 32 * mi;
        p[mi][0] = *(const float4v*)(Pr + k0);
        p[mi][1] = *(const float4v*)(Pr + k0 + 4);
    }

    // Q staging mapping: thread -> rows (tid>>5) and (tid>>5)+8, 4 floats
    int srow = tid >> 5;
    int sc4  = (tid & 31) * 4;
    const float* Qbase = Q + (size_t)(b * L_DIM) * K_DIM;
    const float* Vbase = V + (size_t)(b * L_DIM) * OUT_DIM;

    // prologue: stage tile 0
    *(float4v*)&Qb[0][srow * QSTR + sc4] =
        *(const float4v*)(Qbase + srow * K_DIM + sc4);
    *(float4v*)&Qb[0][(srow + 8) * QSTR + sc4] =
        *(const float4v*)(Qbase + (srow + 8) * K_DIM + sc4);
    __syncthreads();

    float acc[8] = {0,0,0,0,0,0,0,0};
    float sv[8]  = {0,0,0,0,0,0,0,0};

    #pragma unroll 2
    for (int r = 0; r < 8; ++r) {
        int cur = r & 1;

        // next Q tile -> regs (issued early, overlaps compute)
        float4v nq0, nq1;
        if (r < 7) {
            const float* qp = Qbase + (r + 1) * 16 * K_DIM;
            nq0 = *(const float4v*)(qp + srow * K_DIM + sc4);
            nq1 = *(const float4v*)(qp + (srow + 8) * K_DIM + sc4);
        }

        // V for this round: 32 scalars (L2-hot), issued before MFMAs
        const float* Vr = Vbase + (r * 16 + quad * 4) * OUT_DIM + col;
        float vv[32];
        #pragma unroll
        for (int rr = 0; rr < 4; ++rr)
            #pragma unroll
            for (int ct = 0; ct < 8; ++ct)
                vv[rr * 8 + ct] = Vr[rr * OUT_DIM + ct * 16];

        // build this wave's A-fragments: h[j=col][k] = relu(p + Qb[col])
        short8 af[4];
        #pragma unroll
        for (int mi = 0; mi < 4; ++mi) {
            const float* qc = &Qb[cur][col * QSTR + quad * 8 + mi * 32];
            float4v q0 = *(const float4v*)qc;
            float4v q1 = *(const float4v*)(qc + 4);
            short8 a;
            #pragma unroll
            for (int t = 0; t < 4; ++t) {
                a[t]     = bf16_bits(fmaxf(p[mi][0][t] + q0[t], 0.f));
                a[t + 4] = bf16_bits(fmaxf(p[mi][1][t] + q1[t], 0.f));
            }
            af[mi] = a;
        }

        // MFMA + V-scaled reduce
        #pragma unroll
        for (int ct = 0; ct < 8; ++ct) {
            float4v c4 = {0.f, 0.f, 0.f, 0.f};
            #pragma unroll
            for (int mi = 0; mi < 4; ++mi)
                c4 = __builtin_amdgcn_mfma_f32_16x16x32_bf16(
                        af[mi], bfrag[ct][mi], c4, 0, 0, 0);
            #pragma unroll
            for (int rr = 0; rr < 4; ++rr) {
                float v = vv[rr * 8 + ct];
                acc[ct] = fmaf(c4[rr], v, acc[ct]);
                sv[ct] += v;
            }
        }

        // stage next tile into the other buffer; one barrier per round
        if (r < 7) {
            *(float4v*)&Qb[cur ^ 1][srow * QSTR + sc4]       = nq0;
            *(float4v*)&Qb[cur ^ 1][(srow + 8) * QSTR + sc4] = nq1;
        }
        __syncthreads();
    }

    // fold b2*Sv (linear in sv partials), then reduce across quads
    #pragma unroll
    for (int ct = 0; ct < 8; ++ct) {
        float fin = fmaf(attn_b2[ct * 16 + col], sv[ct], acc[ct]);
        fin += __shfl_xor(fin, 16, 64);
        fin += __shfl_xor(fin, 32, 64);
        acc[ct] = fin;
    }

    if (quad == 0) {
        #pragma unroll
        for (int ct = 0; ct < 8; ++ct)
            out[(i_g * N_DIM + b) * OUT_DIM + ct * 16 + col] = acc[ct];
    }
}

// ---------------------------------------------------------------------------
extern "C" void kernel_launch(void* const* d_in, const int* in_sizes, int n_in,
                              void* d_out, int out_size, void* d_ws, size_t ws_size,
                              hipStream_t stream)
{
    const float* x        = (const float*)d_in[0];
    const float* attn_w1  = (const float*)d_in[1];
    const float* attn_b1  = (const float*)d_in[2];
    const float* attn_w2  = (const float*)d_in[3];
    const float* attn_b2  = (const float*)d_in[4];
    const float* value_w1 = (const float*)d_in[5];
    const float* value_b1 = (const float*)d_in[6];
    const float* value_w2 = (const float*)d_in[7];
    const float* value_b2 = (const float*)d_in[8];
    float* out = (float*)d_out;

    // Workspace layout (floats): P 512K | Q 512K | V 512K | W2s(bf16) 16K
    float* ws  = (float*)d_ws;
    float* P   = ws;
    float* Q   = ws + 524288;
    float* V   = ws + 1048576;
    short* W2s = (short*)(ws + 1572864);

    k_pre<<<576, 256, 0, stream>>>(x, attn_w1, attn_b1, attn_w2,
                                   value_w1, value_b1, value_w2, value_b2,
                                   P, Q, V, W2s);
    k_main<<<1024, 256, 0, stream>>>(P, Q, V, W2s, attn_b2, out);
}

// Round 4
// 130.672 us; speedup vs baseline: 1.7119x; 1.7119x over previous
//
#include <hip/hip_runtime.h>
#include <hip/hip_bf16.h>

// Problem constants
#define L_DIM 128
#define N_DIM 32
#define C_DIM 128
#define K_DIM 128   // DIM_MLP
#define OUT_DIM 128

typedef __attribute__((ext_vector_type(8))) short short8;
typedef __attribute__((ext_vector_type(4))) float float4v;

static __device__ __forceinline__ short bf16_bits(float f) {
    __bf16 h = (__bf16)f;   // RNE
    return __builtin_bit_cast(short, h);
}

// ---------------------------------------------------------------------------
// Kernel 1: precompute.
//   blocks 0..255 : 16 flat rows each, weights staged tile-wise via LDS.
//                   P = x·W1a ; Q = x·W1b + b1 ; V = relu(x·Vw1+vb1)·Vw2 + vb2
//   blocks 256..319: W2s = attn_w2 swizzled into bf16 MFMA B-fragment order
// ---------------------------------------------------------------------------
__global__ __launch_bounds__(256) void k_pre(
    const float* __restrict__ x,
    const float* __restrict__ attn_w1, const float* __restrict__ attn_b1,
    const float* __restrict__ attn_w2,
    const float* __restrict__ value_w1, const float* __restrict__ value_b1,
    const float* __restrict__ value_w2, const float* __restrict__ value_b2,
    float* __restrict__ P, float* __restrict__ Q, float* __restrict__ V,
    short* __restrict__ W2s)
{
    int bid = blockIdx.x;
    int tid = threadIdx.x;
    if (bid >= 256) {
        // W2 swizzle: element e = ((((ct*4+mi)*4+quad)*16+col)*8+idx)
        int e = (bid - 256) * 256 + tid;              // 64*256 = 16384 elems
        int idx  = e & 7;
        int colr = (e >> 3) & 15;
        int quad = (e >> 7) & 3;
        int mi   = (e >> 9) & 3;
        int ct   = e >> 11;
        int k = quad * 8 + 32 * mi + idx;
        int c = ct * 16 + colr;
        W2s[e] = bf16_bits(attn_w2[k * OUT_DIM + c]);
        return;
    }

    __shared__ float xs[16][C_DIM];          // 8 KB
    __shared__ float W_lds[3][32][K_DIM];    // 48 KB (weight tiles)
    __shared__ float hvs[16][K_DIM];         // 8 KB

    int r0 = bid * 16;                       // first flat row (i*N+b)

    // cooperative load of 16 x-rows (2048 floats, 2 float4/thread)
    #pragma unroll
    for (int t = 0; t < 2; ++t) {
        int e4 = t * 256 + tid;
        int row = e4 >> 5, c4 = (e4 & 31) * 4;
        *(float4v*)&xs[row][c4] = *(const float4v*)(x + (r0 + row) * C_DIM + c4);
    }

    int ks   = tid & 127;      // output column k (or c)
    int half = tid >> 7;       // rows 0-7 vs 8-15

    float pa[8] = {0,0,0,0,0,0,0,0};
    float qa[8] = {0,0,0,0,0,0,0,0};
    float ha[8] = {0,0,0,0,0,0,0,0};

    for (int ct4 = 0; ct4 < 4; ++ct4) {
        // stage 3 weight tiles: rows ct4*32..+32 of W1a, W1b, Vw1
        #pragma unroll
        for (int t = 0; t < 4; ++t) {
            int e4 = t * 256 + tid;                   // 1024 float4 / matrix
            int cc = e4 >> 5, k4 = (e4 & 31) * 4;
            *(float4v*)&W_lds[0][cc][k4] =
                *(const float4v*)(attn_w1 + (ct4 * 32 + cc) * K_DIM + k4);
            *(float4v*)&W_lds[1][cc][k4] =
                *(const float4v*)(attn_w1 + (C_DIM + ct4 * 32 + cc) * K_DIM + k4);
            *(float4v*)&W_lds[2][cc][k4] =
                *(const float4v*)(value_w1 + (ct4 * 32 + cc) * K_DIM + k4);
        }
        __syncthreads();

        for (int g = 0; g < 8; ++g) {                 // 4-c groups
            float4v xr4[8];
            #pragma unroll
            for (int r = 0; r < 8; ++r)
                xr4[r] = *(const float4v*)&xs[half * 8 + r][ct4 * 32 + g * 4];
            #pragma unroll
            for (int u = 0; u < 4; ++u) {
                int cc = g * 4 + u;
                float wa = W_lds[0][cc][ks];
                float wb = W_lds[1][cc][ks];
                float wv = W_lds[2][cc][ks];
                #pragma unroll
                for (int r = 0; r < 8; ++r) {
                    float xr = xr4[r][u];
                    pa[r] = fmaf(xr, wa, pa[r]);
                    qa[r] = fmaf(xr, wb, qa[r]);
                    ha[r] = fmaf(xr, wv, ha[r]);
                }
            }
        }
        __syncthreads();
    }

    float b1 = attn_b1[ks], vb1 = value_b1[ks];
    #pragma unroll
    for (int r = 0; r < 8; ++r) {
        int rr = r0 + half * 8 + r;
        int i = rr >> 5, b = rr & 31;                  // rr = i*N + b
        P[(b * L_DIM + i) * K_DIM + ks] = pa[r];
        Q[(b * L_DIM + i) * K_DIM + ks] = qa[r] + b1;
        hvs[half * 8 + r][ks] = fmaxf(ha[r] + vb1, 0.f);
    }

    // value second layer: V = hv @ Vw2 + vb2, Vw2 staged tile-wise
    float va[8] = {0,0,0,0,0,0,0,0};
    for (int kt = 0; kt < 4; ++kt) {
        #pragma unroll
        for (int t = 0; t < 4; ++t) {
            int e4 = t * 256 + tid;
            int cc = e4 >> 5, k4 = (e4 & 31) * 4;
            *(float4v*)&W_lds[0][cc][k4] =
                *(const float4v*)(value_w2 + (kt * 32 + cc) * OUT_DIM + k4);
        }
        __syncthreads();
        for (int g = 0; g < 8; ++g) {
            float4v hv4[8];
            #pragma unroll
            for (int r = 0; r < 8; ++r)
                hv4[r] = *(const float4v*)&hvs[half * 8 + r][kt * 32 + g * 4];
            #pragma unroll
            for (int u = 0; u < 4; ++u) {
                float w = W_lds[0][g * 4 + u][ks];
                #pragma unroll
                for (int r = 0; r < 8; ++r)
                    va[r] = fmaf(hv4[r][u], w, va[r]);
            }
        }
        __syncthreads();
    }
    float vb2 = value_b2[ks];
    #pragma unroll
    for (int r = 0; r < 8; ++r) {
        int rr = r0 + half * 8 + r;
        int i = rr >> 5, b = rr & 31;
        V[(b * L_DIM + i) * OUT_DIM + ks] = va[r] + vb2;
    }
}

// ---------------------------------------------------------------------------
// Kernel 2: fused pairwise-MLP + j-reduce, split-K across wave pairs.
//   block = (b, itile); wave w: ipair = w&1 (2 i's), khalf = w>>1 (64 k's).
//   Resident: bfrag[8][2] (64 VGPR), P-slices (32 VGPR) -> no spills.
//   Per round (16 j's): Q tile from dbuf LDS, build A-frags in-reg, 2-chain
//   MFMA (k-partial), V-scale (linear in k-partials), accumulate.
//   End: LDS combine of k-halves + quad shuffle reduce + fold b2*Sv.
// ---------------------------------------------------------------------------
#define QSTR 132   // 128 + 4-float pad

__global__ __launch_bounds__(256)
__attribute__((amdgpu_waves_per_eu(2, 2)))
void k_main(
    const float* __restrict__ P, const float* __restrict__ Q,
    const float* __restrict__ V,
    const short* __restrict__ W2s, const float* __restrict__ attn_b2,
    float* __restrict__ out)
{
    __shared__ float Qb[2][16 * QSTR];       // 16.5 KB double-buffered Q tile
    __shared__ float comb[4 * 8 * 64];       // 8 KB split-K combine

    int b     = blockIdx.x >> 5;
    int itile = blockIdx.x & 31;
    int tid   = threadIdx.x;
    int wave  = tid >> 6;
    int lane  = tid & 63;
    int quad  = lane >> 4;
    int col   = lane & 15;
    int ipair = wave & 1;                    // which i-pair
    int khalf = wave >> 1;                   // which k-half
    int i0    = itile * 4 + ipair * 2;

    // resident B-frags: this wave's k-half of W2, all 8 c-tiles (64 VGPR)
    short8 bfrag[8][2];
    const short8* w2p = (const short8*)W2s;
    #pragma unroll
    for (int ct = 0; ct < 8; ++ct)
        #pragma unroll
        for (int mi = 0; mi < 2; ++mi)
            bfrag[ct][mi] = w2p[((ct * 4 + (khalf * 2 + mi)) * 4 + quad) * 16 + col];

    // resident P slices: 2 i's x k-half (32 VGPR)
    float4v p[2][2][2];
    #pragma unroll
    for (int il = 0; il < 2; ++il) {
        const float* Pr = P + (b * L_DIM + i0 + il) * K_DIM;
        #pragma unroll
        for (int mi = 0; mi < 2; ++mi) {
            int k0 = quad * 8 + (khalf * 2 + mi) * 32;
            p[il][mi][0] = *(const float4v*)(Pr + k0);
            p[il][mi][1] = *(const float4v*)(Pr + k0 + 4);
        }
    }

    // Q staging: thread -> rows (tid>>5) and +8, 4 floats each
    int srow = tid >> 5;
    int sc4  = (tid & 31) * 4;
    const float* Qbase = Q + (size_t)(b * L_DIM) * K_DIM;
    const float* Vbase = V + (size_t)(b * L_DIM) * OUT_DIM;

    *(float4v*)&Qb[0][srow * QSTR + sc4] =
        *(const float4v*)(Qbase + srow * K_DIM + sc4);
    *(float4v*)&Qb[0][(srow + 8) * QSTR + sc4] =
        *(const float4v*)(Qbase + (srow + 8) * K_DIM + sc4);
    __syncthreads();

    float acc[2][8] = {};
    float sv[8]     = {};

    #pragma unroll 1
    for (int r = 0; r < 8; ++r) {
        int cur = r & 1;

        // next Q tile -> regs (overlaps compute)
        float4v nq0, nq1;
        if (r < 7) {
            const float* qp = Qbase + (r + 1) * 16 * K_DIM;
            nq0 = *(const float4v*)(qp + srow * K_DIM + sc4);
            nq1 = *(const float4v*)(qp + (srow + 8) * K_DIM + sc4);
        }

        // V scalars for this round (shared by both i's), L2-hot
        const float* Vr = Vbase + (r * 16 + quad * 4) * OUT_DIM + col;
        float vv[32];
        #pragma unroll
        for (int rr = 0; rr < 4; ++rr)
            #pragma unroll
            for (int ct = 0; ct < 8; ++ct)
                vv[rr * 8 + ct] = Vr[rr * OUT_DIM + ct * 16];

        // build A-frags: h[j=col][k] = relu(p + Q), this wave's k-half
        short8 af[2][2];
        #pragma unroll
        for (int mi = 0; mi < 2; ++mi) {
            const float* qc = &Qb[cur][col * QSTR + quad * 8 + (khalf * 2 + mi) * 32];
            float4v q0 = *(const float4v*)qc;
            float4v q1 = *(const float4v*)(qc + 4);
            #pragma unroll
            for (int il = 0; il < 2; ++il) {
                short8 a;
                #pragma unroll
                for (int t = 0; t < 4; ++t) {
                    a[t]     = bf16_bits(fmaxf(p[il][mi][0][t] + q0[t], 0.f));
                    a[t + 4] = bf16_bits(fmaxf(p[il][mi][1][t] + q1[t], 0.f));
                }
                af[il][mi] = a;
            }
        }

        // k-partial MFMA + V-scaled accumulate (linear -> partials OK)
        #pragma unroll
        for (int ct = 0; ct < 8; ++ct) {
            #pragma unroll
            for (int il = 0; il < 2; ++il) {
                float4v c4 = {0.f, 0.f, 0.f, 0.f};
                c4 = __builtin_amdgcn_mfma_f32_16x16x32_bf16(
                        af[il][0], bfrag[ct][0], c4, 0, 0, 0);
                c4 = __builtin_amdgcn_mfma_f32_16x16x32_bf16(
                        af[il][1], bfrag[ct][1], c4, 0, 0, 0);
                #pragma unroll
                for (int rr = 0; rr < 4; ++rr)
                    acc[il][ct] = fmaf(c4[rr], vv[rr * 8 + ct], acc[il][ct]);
            }
            if (khalf) {   // count V once for the b2*Sv term
                #pragma unroll
                for (int rr = 0; rr < 4; ++rr)
                    sv[ct] += vv[rr * 8 + ct];
            }
        }

        if (r < 7) {
            *(float4v*)&Qb[cur ^ 1][srow * QSTR + sc4]       = nq0;
            *(float4v*)&Qb[cur ^ 1][(srow + 8) * QSTR + sc4] = nq1;
        }
        __syncthreads();
    }

    // ---- split-K combine: khalf0 parks partials, khalf1 finishes ----
    if (khalf == 0) {
        #pragma unroll
        for (int il = 0; il < 2; ++il)
            #pragma unroll
            for (int ct = 0; ct < 8; ++ct)
                comb[((ipair * 2 + il) * 8 + ct) * 64 + lane] = acc[il][ct];
    }
    __syncthreads();
    if (khalf == 1) {
        #pragma unroll
        for (int il = 0; il < 2; ++il) {
            #pragma unroll
            for (int ct = 0; ct < 8; ++ct) {
                float tot = acc[il][ct] +
                            comb[((ipair * 2 + il) * 8 + ct) * 64 + lane];
                tot = fmaf(attn_b2[ct * 16 + col], sv[ct], tot);
                tot += __shfl_xor(tot, 16, 64);
                tot += __shfl_xor(tot, 32, 64);
                if (quad == 0)
                    out[((i0 + il) * N_DIM + b) * OUT_DIM + ct * 16 + col] = tot;
            }
        }
    }
}

// ---------------------------------------------------------------------------
extern "C" void kernel_launch(void* const* d_in, const int* in_sizes, int n_in,
                              void* d_out, int out_size, void* d_ws, size_t ws_size,
                              hipStream_t stream)
{
    const float* x        = (const float*)d_in[0];
    const float* attn_w1  = (const float*)d_in[1];
    const float* attn_b1  = (const float*)d_in[2];
    const float* attn_w2  = (const float*)d_in[3];
    const float* attn_b2  = (const float*)d_in[4];
    const float* value_w1 = (const float*)d_in[5];
    const float* value_b1 = (const float*)d_in[6];
    const float* value_w2 = (const float*)d_in[7];
    const float* value_b2 = (const float*)d_in[8];
    float* out = (float*)d_out;

    // Workspace layout (floats): P 512K | Q 512K | V 512K | W2s(bf16) 16K
    float* ws  = (float*)d_ws;
    float* P   = ws;
    float* Q   = ws + 524288;
    float* V   = ws + 1048576;
    short* W2s = (short*)(ws + 1572864);

    k_pre<<<320, 256, 0, stream>>>(x, attn_w1, attn_b1, attn_w2,
                                   value_w1, value_b1, value_w2, value_b2,
                                   P, Q, V, W2s);
    k_main<<<1024, 256, 0, stream>>>(P, Q, V, W2s, attn_b2, out);
}